// Round 3
// baseline (95.413 us; speedup 1.0000x reference)
//
#include <hip/hip_runtime.h>
#include <math.h>

#define N1 16384
#define N2 16384
#define BLOCK 256
#define PTS 8                          // pos1 points per thread
#define I_BLOCKS (N1 / (BLOCK * PTS))  // 8 blocks along pos1
#define MAX_SLICE_N 1024               // LDS capacity (float4 per pos2 point)
#define UJ 8                           // j-loop prefetch depth (ds_reads in flight)

// Stage 1: partial min over one pos2 slice of g(q) = -2 p.q + |q|^2
// (d^2 = |p|^2 + g; the |p|^2 shift is applied in stage 2).
// LDS holds precomputed (-2qx, -2qy, |q|^2): inner loop = 2 FMA + 1 min/pair.
__global__ __launch_bounds__(BLOCK)
void nn_partial(const float2* __restrict__ pos1,
                const float2* __restrict__ pos2,
                float* __restrict__ partials,
                unsigned int* __restrict__ ticket,
                int slice_n) {
    __shared__ float4 sp[MAX_SLICE_N];
    const int ib = blockIdx.x;
    const int sl = blockIdx.y;
    const int t  = threadIdx.x;

    if (ib == 0 && sl == 0 && t == 0) *ticket = 0;  // init for stage 2

    for (int j = t; j < slice_n; j += BLOCK) {
        float2 q = pos2[sl * slice_n + j];
        sp[j] = make_float4(-2.f * q.x, -2.f * q.y,
                            fmaf(q.x, q.x, q.y * q.y), 0.f);
    }
    __syncthreads();

    const int i0 = ib * (BLOCK * PTS) + t;
    float x[PTS], y[PTS], m[PTS];
#pragma unroll
    for (int k = 0; k < PTS; ++k) {
        float2 p = pos1[i0 + k * BLOCK];
        x[k] = p.x;
        y[k] = p.y;
        m[k] = 3.4e38f;
    }

    for (int j = 0; j < slice_n; j += UJ) {
        float4 qb[UJ];
#pragma unroll
        for (int u = 0; u < UJ; ++u) qb[u] = sp[j + u];  // batched ds_read_b128
#pragma unroll
        for (int u = 0; u < UJ; ++u) {
#pragma unroll
            for (int k = 0; k < PTS; ++k) {
                float g = fmaf(x[k], qb[u].x, fmaf(y[k], qb[u].y, qb[u].z));
                m[k] = fminf(m[k], g);
            }
        }
    }

#pragma unroll
    for (int k = 0; k < PTS; ++k) {
        partials[(size_t)sl * N1 + i0 + k * BLOCK] = m[k];
    }
}

// Stage 2 (fused final): 64 blocks; each thread owns one pos1 point.
// Min over slices (coalesced), + |p|^2, sqrt, block-sum; last block (ticket)
// reduces the 64 block sums and writes the mean.
__global__ __launch_bounds__(BLOCK)
void nn_reduce(const float* __restrict__ partials,
               const float2* __restrict__ pos1,
               float* __restrict__ blocksums,
               unsigned int* __restrict__ ticket,
               float* __restrict__ out,
               int slices) {
    const int t = threadIdx.x;
    const int i = blockIdx.x * BLOCK + t;

    float m = 3.4e38f;
    for (int s = 0; s < slices; ++s) {
        m = fminf(m, partials[(size_t)s * N1 + i]);
    }
    float2 p = pos1[i];
    float d2 = fmaxf(fmaf(p.x, p.x, p.y * p.y) + m, 0.f);
    float sum = sqrtf(d2);

    for (int off = 32; off > 0; off >>= 1) {
        sum += __shfl_down(sum, off, 64);
    }
    __shared__ float wsum[BLOCK / 64];
    __shared__ int lastflag;
    if ((t & 63) == 0) wsum[t >> 6] = sum;
    __syncthreads();
    if (t == 0) {
        float s = 0.f;
        for (int w = 0; w < BLOCK / 64; ++w) s += wsum[w];
        blocksums[blockIdx.x] = s;
        __threadfence();
        unsigned int old = atomicAdd(ticket, 1u);
        lastflag = (old == gridDim.x - 1) ? 1 : 0;
    }
    __syncthreads();
    if (lastflag && t < 64) {
        volatile float* vb = (volatile float*)blocksums;
        float v = vb[t];
        for (int off = 32; off > 0; off >>= 1) {
            v += __shfl_down(v, off, 64);
        }
        if (t == 0) out[0] = v / (float)N1;
    }
}

extern "C" void kernel_launch(void* const* d_in, const int* in_sizes, int n_in,
                              void* d_out, int out_size, void* d_ws, size_t ws_size,
                              hipStream_t stream) {
    const float2* pos1 = (const float2*)d_in[0];
    const float2* pos2 = (const float2*)d_in[1];
    float* out = (float*)d_out;
    float* partials = (float*)d_ws;

    const int nblk2 = N1 / BLOCK;  // 64
    // 128 slices -> 8 MB partials; degrade if ws is smaller.
    int slices = 128;
    while (slices > 1 &&
           (size_t)slices * N1 * sizeof(float) + (nblk2 + 1) * sizeof(float) > ws_size)
        slices >>= 1;
    while (N2 / slices > MAX_SLICE_N) slices <<= 1;
    const int slice_n = N2 / slices;

    float* blocksums = partials + (size_t)slices * N1;
    unsigned int* ticket = (unsigned int*)(blocksums + nblk2);

    dim3 grid1(I_BLOCKS, slices);
    nn_partial<<<grid1, BLOCK, 0, stream>>>(pos1, pos2, partials, ticket, slice_n);
    nn_reduce<<<nblk2, BLOCK, 0, stream>>>(partials, pos1, blocksums, ticket, out, slices);
}